// Round 6
// baseline (368.050 us; speedup 1.0000x reference)
//
#include <hip/hip_runtime.h>
#include <hip/hip_bf16.h>

// Problem constants (match reference file)
constexpr int K    = 8192;
constexpr int N4   = 6144;    // int4 rows
constexpr int N8   = 2048;    // uint8 rows
constexpr int NT   = N4 + N8; // 8192 output columns
constexpr int NG   = K / 128; // 64 groups per int4 row

typedef short  short8  __attribute__((ext_vector_type(8)));
typedef float  floatx4 __attribute__((ext_vector_type(4)));

__device__ inline short f2bf(float f) {
    __hip_bfloat16 h = __float2bfloat16(f);   // RNE
    return __builtin_bit_cast(short, h);
}

// ---------------------------------------------------------------------------
// Prep: x2bf = bf16(x/awq) stored in MFMA A-fragment order:
//   x2bf[c*512 + lane*8 + j] = X[m = lane&15][k = c*32 + (lane>>4)*8 + j]
// Also: fwd = inverse of inv_perm.
// ---------------------------------------------------------------------------
__global__ void prep_kernel(const float* __restrict__ x,
                            const float* __restrict__ awq,
                            const int*   __restrict__ inv_perm,
                            short* __restrict__ x2bf,
                            int*   __restrict__ fwd) {
    const int tid  = blockIdx.x * blockDim.x + threadIdx.x;   // 0..131071
    const int c    = tid >> 9;
    const int rem  = tid & 511;
    const int lane = rem >> 3;
    const int j    = rem & 7;
    const int m    = lane & 15;
    const int k    = c * 32 + (lane >> 4) * 8 + j;
    x2bf[tid] = f2bf(x[m * K + k] / awq[k]);
    if (tid < NT) fwd[inv_perm[tid]] = tid;
}

// ---------------------------------------------------------------------------
// MFMA dot-chunk with deferred scale: B-fragment = bf16(w + off), off = -8
// (int4) or -128 (uint8 nibble-merge). Raw ints are EXACT in bf16; the group
// scale is applied in f32 on the 64-k partial sum afterwards.
// ---------------------------------------------------------------------------
__device__ inline floatx4 chunk_mfma(int4 wa, int4 wb, short8 xv, float off,
                                     floatx4 cin) {
    short8 bf;
    bf[0] = f2bf((float)wa.x + off);
    bf[1] = f2bf((float)wa.y + off);
    bf[2] = f2bf((float)wa.z + off);
    bf[3] = f2bf((float)wa.w + off);
    bf[4] = f2bf((float)wb.x + off);
    bf[5] = f2bf((float)wb.y + off);
    bf[6] = f2bf((float)wb.z + off);
    bf[7] = f2bf((float)wb.w + off);
    return __builtin_amdgcn_mfma_f32_16x16x32_bf16(xv, bf, cin, 0, 0, 0);
}

// ---------------------------------------------------------------------------
// Single-pass MFMA GEMV. Block = 8 waves (512 thr) = one 16-row tile; wave w
// owns k in [w*1024, w*1024+1024) as 16 stages of 64 k (2 chunks of 32 k).
// Explicit 2-stage ping-pong with INDIVIDUALLY NAMED registers (no arrays /
// lambdas) so the allocator keeps 6 loads in flight per wave while the
// previous stage computes. 4 waves/SIMD occupancy. No barriers in the K-loop,
// no atomics: 8-way LDS reduce + single permuted/biased store per element.
//   int4 rows : acc += s4[row,g] * (sum_k x[m,k]*(w-8))
//   uint8 rows: acc += s8[row]   * (sum_k x[m,k]*(w-128))   (nibble merge)
// ---------------------------------------------------------------------------
__global__ __launch_bounds__(512)
void qgemv_kernel(const short* __restrict__ xf,
                  const int*   __restrict__ w4,
                  const float* __restrict__ s4,
                  const int*   __restrict__ w8,
                  const float* __restrict__ s8,
                  const int*   __restrict__ fwd,
                  const float* __restrict__ bias,
                  float* __restrict__ out) {
    __shared__ float lds[8 * 256];

    const int t    = threadIdx.x;
    const int lane = t & 63;
    const int w    = t >> 6;            // wave 0..7
    const int nb   = blockIdx.x * 16;   // tile base row (tile type uniform)
    const int i    = lane & 15;
    const int q    = lane >> 4;
    const int row  = nb + i;            // this lane's weight row / output col

    const bool  is4 = (nb < N4);
    const float off = is4 ? -8.f : -128.f;

    const int*   wp = (is4 ? (w4 + (size_t)row * K)
                           : (w8 + (size_t)(row - N4) * K))
                      + w * 1024 + q * 8;            // + chunk*32 later
    const short* xw = xf + ((size_t)w * 32) * 512 + lane * 8;  // + chunk*512
    const float* sp = s4 + (size_t)row * NG + w * 8;           // + stage>>1
    const float  s8row = is4 ? 0.f : s8[row - N4];

    floatx4 acc = {0.f, 0.f, 0.f, 0.f};

    int4   wA0, wA1, wA2, wA3, wB0, wB1, wB2, wB3;
    short8 xA0, xA1, xB0, xB1;
    float  sA, sB;

#define LOADSTAGE(S, W0, W1, W2, W3, X0, X1, SS)                     \
    do {                                                             \
        const int c_ = 2 * (S);                                      \
        W0 = *(const int4*)(wp + (size_t)c_ * 32);                   \
        W1 = *(const int4*)(wp + (size_t)c_ * 32 + 4);               \
        W2 = *(const int4*)(wp + (size_t)c_ * 32 + 32);              \
        W3 = *(const int4*)(wp + (size_t)c_ * 32 + 36);              \
        X0 = *(const short8*)(xw + (size_t)c_ * 512);                \
        X1 = *(const short8*)(xw + (size_t)c_ * 512 + 512);          \
        SS = is4 ? sp[(S) >> 1] : s8row;                             \
    } while (0)

#define COMPSTAGE(W0, W1, W2, W3, X0, X1, SS)                        \
    do {                                                             \
        floatx4 g_ = chunk_mfma(W0, W1, X0, off,                     \
                                (floatx4){0.f, 0.f, 0.f, 0.f});      \
        g_ = chunk_mfma(W2, W3, X1, off, g_);                        \
        acc[0] += (SS) * g_[0];                                      \
        acc[1] += (SS) * g_[1];                                      \
        acc[2] += (SS) * g_[2];                                      \
        acc[3] += (SS) * g_[3];                                      \
    } while (0)

    LOADSTAGE(0, wA0, wA1, wA2, wA3, xA0, xA1, sA);
    #pragma unroll 1
    for (int s = 0; s < 16; s += 2) {
        const int s1 = (s + 1 < 16) ? s + 1 : 15;
        LOADSTAGE(s1, wB0, wB1, wB2, wB3, xB0, xB1, sB);
        COMPSTAGE(wA0, wA1, wA2, wA3, xA0, xA1, sA);
        const int s2 = (s + 2 < 16) ? s + 2 : 15;   // last iter: dummy reload
        LOADSTAGE(s2, wA0, wA1, wA2, wA3, xA0, xA1, sA);
        COMPSTAGE(wB0, wB1, wB2, wB3, xB0, xB1, sB);
    }
#undef LOADSTAGE
#undef COMPSTAGE

    // ---- 8-way cross-wave reduce + fused perm/bias writeout ----
    #pragma unroll
    for (int r = 0; r < 4; ++r)
        lds[w * 256 + (q * 4 + r) * 16 + i] = acc[r];
    __syncthreads();

    if (t < 256) {
        float v = 0.f;
        #pragma unroll
        for (int ww = 0; ww < 8; ++ww) v += lds[ww * 256 + t];
        const int m  = t >> 4;     // batch row
        const int i2 = t & 15;     // tile col
        const int n  = nb + i2;
        const int d  = fwd[n];
        out[(size_t)m * NT + d] = v + bias[d];
    }
}

// ---------------------------------------------------------------------------
extern "C" void kernel_launch(void* const* d_in, const int* in_sizes, int n_in,
                              void* d_out, int out_size, void* d_ws, size_t ws_size,
                              hipStream_t stream) {
    const float* x        = (const float*)d_in[0];
    const int*   w_int4   = (const int*)  d_in[1];
    const float* s_int4   = (const float*)d_in[2];
    const int*   w_uint8  = (const int*)  d_in[3];
    const float* s_int8   = (const float*)d_in[4];
    const float* awq      = (const float*)d_in[5];
    const float* bias     = (const float*)d_in[6];
    const int*   inv_perm = (const int*)  d_in[7];
    // d_in[8] = group_size (==128), compile-time constant here

    short* x2bf = (short*)d_ws;                                        // 256 KB
    int*   fwd  = (int*)((char*)d_ws + (size_t)16 * K * sizeof(short)); // 32 KB

    prep_kernel<<<(16 * K) / 256, 256, 0, stream>>>(x, awq, inv_perm, x2bf, fwd);
    qgemv_kernel<<<NT / 16, 512, 0, stream>>>(x2bf, w_int4, s_int4,
                                              w_uint8, s_int8, fwd, bias,
                                              (float*)d_out);
}

// Round 7
// 339.356 us; speedup vs baseline: 1.0846x; 1.0846x over previous
//
#include <hip/hip_runtime.h>
#include <hip/hip_bf16.h>

// Problem constants (match reference file)
constexpr int K    = 8192;
constexpr int N4   = 6144;    // int4 rows
constexpr int N8   = 2048;    // uint8 rows
constexpr int NT   = N4 + N8; // 8192 output columns
constexpr int NG   = K / 128; // 64 groups per int4 row

typedef short  short8  __attribute__((ext_vector_type(8)));
typedef float  floatx4 __attribute__((ext_vector_type(4)));
typedef __attribute__((address_space(1))) void gas_t;
typedef __attribute__((address_space(3))) void las_t;

__device__ inline short f2bf(float f) {
    __hip_bfloat16 h = __float2bfloat16(f);   // RNE
    return __builtin_bit_cast(short, h);
}

// Direct global->LDS DMA, 16 B per lane; LDS dest = uniform base + lane*16.
__device__ __forceinline__ void dma16(const void* g, void* l) {
    __builtin_amdgcn_global_load_lds((gas_t*)g, (las_t*)l, 16, 0, 0);
}

// s_waitcnt: vmcnt = N (bits [3:0], N<=15 here), lgkmcnt = 0 (free at our call
// sites: previous ds_reads already consumed), expcnt = 7 (unconstrained).
#define WAIT_VM(N) __builtin_amdgcn_s_waitcnt(0x70 | (N))

// ---------------------------------------------------------------------------
// Prep: x2bf = bf16(x/awq) stored in MFMA A-fragment order:
//   x2bf[c*512 + lane*8 + j] = X[m = lane&15][k = c*32 + (lane>>4)*8 + j]
// Also: fwd = inverse of inv_perm.
// ---------------------------------------------------------------------------
__global__ void prep_kernel(const float* __restrict__ x,
                            const float* __restrict__ awq,
                            const int*   __restrict__ inv_perm,
                            short* __restrict__ x2bf,
                            int*   __restrict__ fwd) {
    const int tid  = blockIdx.x * blockDim.x + threadIdx.x;   // 0..131071
    const int c    = tid >> 9;
    const int rem  = tid & 511;
    const int lane = rem >> 3;
    const int j    = rem & 7;
    const int m    = lane & 15;
    const int k    = c * 32 + (lane >> 4) * 8 + j;
    x2bf[tid] = f2bf(x[m * K + k] / awq[k]);
    if (tid < NT) fwd[inv_perm[tid]] = tid;
}

// ---------------------------------------------------------------------------
// MFMA dot-chunk, deferred scale: B = bf16(w + off), off = -8 (int4) or -128
// (uint8 nibble merge; exact in bf16). Group scale applied on 64-k partials.
// ---------------------------------------------------------------------------
__device__ __forceinline__ floatx4 chunk_mfma(int4 wa, int4 wb, short8 xv,
                                              float off, floatx4 cin) {
    short8 bf;
    bf[0] = f2bf((float)wa.x + off);
    bf[1] = f2bf((float)wa.y + off);
    bf[2] = f2bf((float)wa.z + off);
    bf[3] = f2bf((float)wa.w + off);
    bf[4] = f2bf((float)wb.x + off);
    bf[5] = f2bf((float)wb.y + off);
    bf[6] = f2bf((float)wb.z + off);
    bf[7] = f2bf((float)wb.w + off);
    return __builtin_amdgcn_mfma_f32_16x16x32_bf16(xv, bf, cin, 0, 0, 0);
}

// ---------------------------------------------------------------------------
// DMA-pipelined MFMA GEMV. Block = 4 waves = one 16-row tile; wave w owns
// k in [w*2048, (w+1)*2048) as 32 stages of 64 k. Each wave streams weights +
// x-fragments via global_load_lds into a PRIVATE 3-slot LDS ring (three
// distinct __shared__ arrays so the waitcnt pass can disambiguate slots), with
// explicit s_waitcnt vmcnt(12): 2 stages (12 DMA ops) always in flight, zero
// VGPR cost for in-flight data, NO barriers in the K-loop.
//   int4 rows : acc += s4[row,g] * (sum_k x[m,k]*(w-8))
//   uint8 rows: acc += s8[row]   * (sum_k x[m,k]*(w-128))   (nibble merge)
// ---------------------------------------------------------------------------
__global__ __launch_bounds__(256)
void qgemv_kernel(const short* __restrict__ xf,
                  const int*   __restrict__ w4,
                  const float* __restrict__ s4,
                  const int*   __restrict__ w8,
                  const float* __restrict__ s8,
                  const int*   __restrict__ fwd,
                  const float* __restrict__ bias,
                  float* __restrict__ out) {
    // 3-slot ring, distinct objects: [wave][data]
    __shared__ int   wsl0[4][1024], wsl1[4][1024], wsl2[4][1024]; // 48 KB
    __shared__ short xsl0[4][1024], xsl1[4][1024], xsl2[4][1024]; // 24 KB
    __shared__ float scl[4][256];                                 //  4 KB
    __shared__ float red[4][256];                                 //  4 KB

    const int t    = threadIdx.x;
    const int lane = t & 63;
    const int w    = t >> 6;            // wave 0..3
    const int nb   = blockIdx.x * 16;   // tile base row (type uniform)
    const int i    = lane & 15;
    const int q    = lane >> 4;
    const int row  = nb + i;

    const bool  is4 = (nb < N4);
    const float off = is4 ? -8.f : -128.f;

    // Per-lane global pointers. Weight DMA j covers (chunk c=j>>1, half h=j&1):
    // lane (i,q) loads w[row i][kbase + c*32 + q*8 + h*4 .. +3] -> LDS lane*16,
    // so each lane stages exactly its own B-fragment pieces.
    const int*   pw = (is4 ? (w4 + (size_t)row * K)
                           : (w8 + (size_t)(row - N4) * K)) + w * 2048 + q * 8;
    const short* px = xf + (size_t)w * 64 * 512 + lane * 8;
    const float  s8row = is4 ? 0.f : s8[row - N4];

    // Scale DMA (1 KB/wave, once): lane ld stages s4[nb + (ld>>2)][w*16 + (ld&3)*4 ..+3]
    // -> scl[w][(ld>>2)*16 + (ld&3)*4] (identity with dest ld*16 B).
    if (is4) {
        const float* ps = s4 + (size_t)(nb + (lane >> 2)) * NG + w * 16 + (lane & 3) * 4;
        dma16(ps, &scl[w][0]);
    }

#define ISSUE(S, WSL, XSL)                                            \
    do {                                                              \
        const int*   pws = pw + (S) * 64;                             \
        const short* pxs = px + (size_t)(2 * (S)) * 512;              \
        dma16(pws,      &WSL[w][0]);                                  \
        dma16(pws + 4,  &WSL[w][256]);                                \
        dma16(pws + 32, &WSL[w][512]);                                \
        dma16(pws + 36, &WSL[w][768]);                                \
        dma16(pxs,       &XSL[w][0]);                                 \
        dma16(pxs + 512, &XSL[w][512]);                               \
    } while (0)

#define BODY(S, WSL, XSL, NWAIT)                                      \
    do {                                                              \
        WAIT_VM(NWAIT);                                               \
        const int*   wsrc = &WSL[w][0];                               \
        const short* xsrc = &XSL[w][0];                               \
        const int4   wv0 = *(const int4*)(wsrc + lane * 4);           \
        const int4   wv1 = *(const int4*)(wsrc + 256 + lane * 4);     \
        const int4   wv2 = *(const int4*)(wsrc + 512 + lane * 4);     \
        const int4   wv3 = *(const int4*)(wsrc + 768 + lane * 4);     \
        const short8 xv0 = *(const short8*)(xsrc + lane * 8);         \
        const short8 xv1 = *(const short8*)(xsrc + 512 + lane * 8);   \
        const float  sg  = is4 ? scl[w][i * 16 + ((S) >> 1)] : s8row; \
        floatx4 g_ = chunk_mfma(wv0, wv1, xv0, off,                   \
                                (floatx4){0.f, 0.f, 0.f, 0.f});       \
        g_ = chunk_mfma(wv2, wv3, xv1, off, g_);                      \
        acc[0] += sg * g_[0]; acc[1] += sg * g_[1];                   \
        acc[2] += sg * g_[2]; acc[3] += sg * g_[3];                   \
    } while (0)

    floatx4 acc = {0.f, 0.f, 0.f, 0.f};

    // Prologue: 3 stages in flight (18 DMA ops + 1 scale op).
    ISSUE(0, wsl0, xsl0);
    ISSUE(1, wsl1, xsl1);
    ISSUE(2, wsl2, xsl2);

    // Steady state: consume stage s (wait vmcnt(12): stages s+1, s+2 = 12 ops
    // stay in flight), then re-issue its slot for stage s+3.
    #pragma unroll 1
    for (int s = 0; s < 27; s += 3) {
        BODY(s,     wsl0, xsl0, 12); ISSUE(s + 3, wsl0, xsl0);
        BODY(s + 1, wsl1, xsl1, 12); ISSUE(s + 4, wsl1, xsl1);
        BODY(s + 2, wsl2, xsl2, 12); ISSUE(s + 5, wsl2, xsl2);
    }
    BODY(27, wsl0, xsl0, 12); ISSUE(30, wsl0, xsl0);
    BODY(28, wsl1, xsl1, 12); ISSUE(31, wsl1, xsl1);
    BODY(29, wsl2, xsl2, 12);
    BODY(30, wsl0, xsl0, 6);
    BODY(31, wsl1, xsl1, 0);

#undef ISSUE
#undef BODY

    // ---- cross-wave reduce + fused perm/bias writeout ----
    #pragma unroll
    for (int r = 0; r < 4; ++r)
        red[w][(q * 4 + r) * 16 + i] = acc[r];
    __syncthreads();

    if (t < 256) {
        const float v = red[0][t] + red[1][t] + red[2][t] + red[3][t];
        const int m  = t >> 4;     // batch row
        const int i2 = t & 15;     // tile col
        const int n  = nb + i2;
        const int d  = fwd[n];
        out[(size_t)m * NT + d] = v + bias[d];
    }
}

// ---------------------------------------------------------------------------
extern "C" void kernel_launch(void* const* d_in, const int* in_sizes, int n_in,
                              void* d_out, int out_size, void* d_ws, size_t ws_size,
                              hipStream_t stream) {
    const float* x        = (const float*)d_in[0];
    const int*   w_int4   = (const int*)  d_in[1];
    const float* s_int4   = (const float*)d_in[2];
    const int*   w_uint8  = (const int*)  d_in[3];
    const float* s_int8   = (const float*)d_in[4];
    const float* awq      = (const float*)d_in[5];
    const float* bias     = (const float*)d_in[6];
    const int*   inv_perm = (const int*)  d_in[7];
    // d_in[8] = group_size (==128), compile-time constant here

    short* x2bf = (short*)d_ws;                                        // 256 KB
    int*   fwd  = (int*)((char*)d_ws + (size_t)16 * K * sizeof(short)); // 32 KB

    prep_kernel<<<(16 * K) / 256, 256, 0, stream>>>(x, awq, inv_perm, x2bf, fwd);
    qgemv_kernel<<<NT / 16, 256, 0, stream>>>(x2bf, w_int4, s_int4,
                                              w_uint8, s_int8, fwd, bias,
                                              (float*)d_out);
}

// Round 8
// 338.048 us; speedup vs baseline: 1.0888x; 1.0039x over previous
//
#include <hip/hip_runtime.h>
#include <hip/hip_bf16.h>

// Problem constants (match reference file)
constexpr int K    = 8192;
constexpr int N4   = 6144;    // int4 rows
constexpr int N8   = 2048;    // uint8 rows
constexpr int NT   = N4 + N8; // 8192 output columns
constexpr int NG   = K / 128; // 64 groups per int4 row
constexpr int WSTR = 258;     // LDS w-row stride in ints (+2 pad: 2-way banks = free)

typedef short  short8  __attribute__((ext_vector_type(8)));
typedef float  floatx4 __attribute__((ext_vector_type(4)));
typedef __attribute__((address_space(1))) void gas_t;
typedef __attribute__((address_space(3))) void las_t;

__device__ inline short f2bf(float f) {
    __hip_bfloat16 h = __float2bfloat16(f);   // RNE
    return __builtin_bit_cast(short, h);
}

// global->LDS DMA: each lane reads 16 B at its own global addr; lands at
// (wave-uniform) LDS base + lane*16.
__device__ __forceinline__ void dma16(const void* g, void* l) {
    __builtin_amdgcn_global_load_lds((gas_t*)g, (las_t*)l, 16, 0, 0);
}

// ---------------------------------------------------------------------------
// Prep: x2bf = bf16(x/awq) in MFMA A-fragment order:
//   x2bf[c*512 + lane*8 + j] = X[m = lane&15][k = c*32 + (lane>>4)*8 + j]
// fwd = inverse of inv_perm ; out = bias broadcast (qgemv atomics add on top).
// ---------------------------------------------------------------------------
__global__ void prep_kernel(const float* __restrict__ x,
                            const float* __restrict__ awq,
                            const int*   __restrict__ inv_perm,
                            const float* __restrict__ bias,
                            short* __restrict__ x2bf,
                            int*   __restrict__ fwd,
                            float* __restrict__ out) {
    const int tid  = blockIdx.x * blockDim.x + threadIdx.x;   // 0..131071
    const int c    = tid >> 9;
    const int rem  = tid & 511;
    const int lane = rem >> 3;
    const int j    = rem & 7;
    const int m    = lane & 15;
    const int k    = c * 32 + (lane >> 4) * 8 + j;
    x2bf[tid] = f2bf(x[m * K + k] / awq[k]);
    out[tid]  = bias[tid & (NT - 1)];
    if (tid < NT) fwd[inv_perm[tid]] = tid;
}

// ---------------------------------------------------------------------------
// MFMA dot-chunk, deferred scale: B = bf16(w + off), off = -8 (int4) or -128
// (uint8 nibble merge; exact in bf16). Group scale applied on partial sums.
// ---------------------------------------------------------------------------
__device__ __forceinline__ floatx4 chunk_mfma(int4 wa, int4 wb, short8 xv,
                                              float off, floatx4 cin) {
    short8 bf;
    bf[0] = f2bf((float)wa.x + off);
    bf[1] = f2bf((float)wa.y + off);
    bf[2] = f2bf((float)wa.z + off);
    bf[3] = f2bf((float)wa.w + off);
    bf[4] = f2bf((float)wb.x + off);
    bf[5] = f2bf((float)wb.y + off);
    bf[6] = f2bf((float)wb.z + off);
    bf[7] = f2bf((float)wb.w + off);
    return __builtin_amdgcn_mfma_f32_16x16x32_bf16(xv, bf, cin, 0, 0, 0);
}

// ---------------------------------------------------------------------------
// m97-pattern staging GEMV. Block = 4 waves = 16 rows x 4096 k (split-K 2,
// 1024 blocks, ALL resident: ~37 KB LDS -> 4 blocks/CU, independent barriers
// per block give the cross-block overlap that hides each block's DMA drain).
// Per iter (256 k): issue next w-tile via global_load_lds into the other LDS
// buffer (4 x 1KB DMA/wave), barrier (drains own DMA), consume: wave w takes
// chunks {2w,2w+1}, reads w-frags from LDS (2-way banks = free), x-frags as
// per-lane global short8 (L2-hot), 2 MFMA + deferred group scale, barrier.
//   int4 rows : acc += s4[row,g] * (sum_k x[m,k]*(w-8))
//   uint8 rows: acc += s8[row]   * (sum_k x[m,k]*(w-128))   (nibble merge)
// Epilogue: 4-wave LDS reduce + one unsafeAtomicAdd per output element
// (out pre-initialized with bias by prep).
// ---------------------------------------------------------------------------
__global__ __launch_bounds__(256)
void qgemv_kernel(const short* __restrict__ xf,
                  const int*   __restrict__ w4,
                  const float* __restrict__ s4,
                  const int*   __restrict__ w8,
                  const float* __restrict__ s8,
                  const int*   __restrict__ fwd,
                  float* __restrict__ out) {
    __shared__ int   wbuf[2][16 * WSTR];   // 33 KB (double-buffered w-tile)
    __shared__ float red[4][256];          //  4 KB

    const int t    = threadIdx.x;
    const int lane = t & 63;
    const int w    = t >> 6;               // wave 0..3
    const int tile = blockIdx.x >> 1;      // 0..511
    const int spl  = blockIdx.x & 1;       // k-split 0..1
    const int nb   = tile * 16;
    const int i    = lane & 15;
    const int q    = lane >> 4;
    const int row  = nb + i;

    const bool  is4 = (nb < N4);
    const float off = is4 ? -8.f : -128.f;
    const float s8row = is4 ? 0.f : s8[row - N4];
    const int   kb  = spl * 4096;

    const int* wbase = is4 ? (w4 + (size_t)nb * K) : (w8 + (size_t)(nb - N4) * K);

    floatx4 acc = {0.f, 0.f, 0.f, 0.f};

    // Issue iter 0 into buffer 0. Wave w stages rows {w, w+4, w+8, w+12}:
    // lane l reads global k-elems [it*256 + 4l .. +3] of its row -> LDS row slice.
    #pragma unroll
    for (int a = 0; a < 4; ++a) {
        const int r = w + 4 * a;
        dma16(wbase + (size_t)r * K + kb + lane * 4, &wbuf[0][r * WSTR]);
    }

    #pragma unroll 1
    for (int it = 0; it < 16; ++it) {
        // issue next iter's tile into the other buffer (clamped dummy on last)
        const int nxt = (it + 1 < 16) ? it + 1 : 15;
        #pragma unroll
        for (int a = 0; a < 4; ++a) {
            const int r = w + 4 * a;
            dma16(wbase + (size_t)r * K + kb + nxt * 256 + lane * 4,
                  &wbuf[(it + 1) & 1][r * WSTR]);
        }

        // per-lane group scale for this wave's chunks (both chunks same group)
        const int   g  = spl * 32 + it * 2 + (w >> 1);
        const float sg = is4 ? s4[(size_t)row * NG + g] : s8row;

        __syncthreads();   // own-DMA vmcnt(0) drain: buffer it&1 complete

        const int* wb = &wbuf[it & 1][0];
        floatx4 gacc = {0.f, 0.f, 0.f, 0.f};
        #pragma unroll
        for (int cc = 0; cc < 2; ++cc) {
            const int c   = 2 * w + cc;                      // chunk 0..7
            const int4 wv0 = *(const int4*)(wb + i * WSTR + c * 32 + q * 8);
            const int4 wv1 = *(const int4*)(wb + i * WSTR + c * 32 + q * 8 + 4);
            const short8 xv = *(const short8*)(xf + (size_t)(spl * 128 + it * 8 + c) * 512
                                               + lane * 8);
            gacc = chunk_mfma(wv0, wv1, xv, off, gacc);
        }
        acc[0] += sg * gacc[0]; acc[1] += sg * gacc[1];
        acc[2] += sg * gacc[2]; acc[3] += sg * gacc[3];

        __syncthreads();   // all waves done reading buf[it&1] before re-DMA
    }

    // ---- cross-wave reduce + atomic writeout (out pre-init = bias) ----
    #pragma unroll
    for (int r = 0; r < 4; ++r)
        red[w][(q * 4 + r) * 16 + i] = acc[r];
    __syncthreads();

    if (t < 256) {
        const float v = red[0][t] + red[1][t] + red[2][t] + red[3][t];
        const int m  = t >> 4;     // batch row
        const int i2 = t & 15;     // tile col
        const int d  = fwd[nb + i2];
        unsafeAtomicAdd(&out[(size_t)m * NT + d], v);
    }
}

// ---------------------------------------------------------------------------
extern "C" void kernel_launch(void* const* d_in, const int* in_sizes, int n_in,
                              void* d_out, int out_size, void* d_ws, size_t ws_size,
                              hipStream_t stream) {
    const float* x        = (const float*)d_in[0];
    const int*   w_int4   = (const int*)  d_in[1];
    const float* s_int4   = (const float*)d_in[2];
    const int*   w_uint8  = (const int*)  d_in[3];
    const float* s_int8   = (const float*)d_in[4];
    const float* awq      = (const float*)d_in[5];
    const float* bias     = (const float*)d_in[6];
    const int*   inv_perm = (const int*)  d_in[7];
    // d_in[8] = group_size (==128), compile-time constant here

    short* x2bf = (short*)d_ws;                                        // 256 KB
    int*   fwd  = (int*)((char*)d_ws + (size_t)16 * K * sizeof(short)); // 32 KB

    prep_kernel<<<(16 * K) / 256, 256, 0, stream>>>(x, awq, inv_perm, bias,
                                                    x2bf, fwd, (float*)d_out);
    // 512 tiles x 2 k-splits = 1024 blocks of 4 waves (4 resident/CU)
    qgemv_kernel<<<1024, 256, 0, stream>>>(x2bf, w_int4, s_int4,
                                           w_uint8, s_int8, fwd,
                                           (float*)d_out);
}